// Round 6
// baseline (7920.294 us; speedup 1.0000x reference)
//
#include <hip/hip_runtime.h>
#include <stdint.h>

typedef __attribute__((ext_vector_type(8))) short short8;
typedef __attribute__((ext_vector_type(4))) float floatx4;

#define DEVINL __device__ __forceinline__

DEVINL unsigned short f2bf(float f) {
    unsigned int u = __float_as_uint(f);
    u += 0x7FFFu + ((u >> 16) & 1u);
    return (unsigned short)(u >> 16);
}
DEVINL float bf2f(unsigned short h) {
    return __uint_as_float(((unsigned int)h) << 16);
}
DEVINL float sigf(float x)     { return 1.0f / (1.0f + __expf(-x)); }
DEVINL float tanhfast(float x) { return 2.0f / (1.0f + __expf(-2.0f * x)) - 1.0f; }

// ---------------- problem constants ----------------
constexpr int L_SEQ = 256, BATCH = 16, HID = 800, NGATE = 3200, DIN = 42, NALPHA = 20;
constexpr int HSLOT = BATCH * HID;          // 12800 elements per time slot
constexpr int NBLK_SCAN = 200;              // 2 dirs x 100 j-chunks (8 hidden units each)

// ---------------- workspace layout (bytes) ----------------
constexpr size_t OFF_CNT     = 0;                                   // (reserved)
constexpr size_t SZ_WHH_L    = 10240000;                            // per layer: 2*3200*800*2B
constexpr size_t OFF_WHH_HI  = 4096;                                // 2 layers
constexpr size_t OFF_WHH_LO  = OFF_WHH_HI + 2 * SZ_WHH_L;
constexpr size_t SZ_WIH1     = 20480000;                            // 2*3200*1600*2B
constexpr size_t OFF_WIH1_HI = OFF_WHH_LO + 2 * SZ_WHH_L;
constexpr size_t OFF_WIH1_LO = OFF_WIH1_HI + SZ_WIH1;
constexpr size_t OFF_PRE     = OFF_WIH1_LO + SZ_WIH1;               // fp32, shared pre0/pre1
constexpr size_t SZ_PRE      = (size_t)2 * L_SEQ * BATCH * NGATE * 4;  // 104,857,600
constexpr size_t SZ_HP       = (size_t)257 * HSLOT * 4;             // 13,158,400 per packed buf
constexpr size_t OFF_H       = OFF_PRE + SZ_PRE;                    // 4 bufs: F, B, 2F, 2B
constexpr size_t OFF_ANG     = OFF_H + 4 * SZ_HP;                   // 256*16*3 fp32
// total ~228.4 MiB

// =====================================================================
// Pack W_hh (fp32 [2][3200][800]) into hi/lo MFMA B-fragment streams.
// =====================================================================
__global__ __launch_bounds__(256) void pack_whh_kernel(
    const float* __restrict__ w0, const float* __restrict__ w1,
    unsigned short* __restrict__ hi, unsigned short* __restrict__ lo)
{
    size_t g = (size_t)blockIdx.x * 256 + threadIdx.x;   // 1,280,000 total
    if (g >= 1280000) return;
    int l = (int)(g & 63);
    size_t gg = g >> 6;                                   // 20000 fragment ids
    int kk = (int)(gg % 25); gg /= 25;
    int nt = (int)(gg % 2);  gg /= 2;
    int jc = (int)(gg % 100); gg /= 100;
    int d  = (int)(gg % 2);
    int layer = (int)(gg / 2);
    const float* W = layer ? w1 : w0;
    int lr = nt * 16 + (l & 15);
    int gate = lr >> 3, jj = lr & 7;
    int r  = gate * 800 + jc * 8 + jj;
    int k0 = kk * 32 + (l >> 4) * 8;
    const float* s = W + ((size_t)d * NGATE + r) * HID + k0;
    short8 vh, vl;
    #pragma unroll
    for (int j = 0; j < 8; ++j) {
        float w = s[j];
        unsigned short h = f2bf(w);
        vh[j] = (short)h;
        vl[j] = (short)f2bf(w - bf2f(h));
    }
    size_t idx = (size_t)layer * 640000 + ((size_t)d * 100 + jc) * 3200
               + (size_t)(nt * 25 + kk) * 64 + l;
    ((short8*)hi)[idx] = vh;
    ((short8*)lo)[idx] = vl;
}

// =====================================================================
// fp32 -> hi/lo bf16 conversion of w_ih_l1 (flat [2][3200][1600]).
// =====================================================================
__global__ __launch_bounds__(256) void conv_wih1_kernel(
    const float* __restrict__ w, unsigned short* __restrict__ hi,
    unsigned short* __restrict__ lo)
{
    size_t g = (size_t)blockIdx.x * 256 + threadIdx.x;   // 1,280,000 groups of 8
    if (g >= 1280000) return;
    const float* s = w + g * 8;
    short8 vh, vl;
    #pragma unroll
    for (int j = 0; j < 8; ++j) {
        float x = s[j];
        unsigned short h = f2bf(x);
        vh[j] = (short)h;
        vl[j] = (short)f2bf(x - bf2f(h));
    }
    ((short8*)hi)[g] = vh;
    ((short8*)lo)[g] = vl;
}

// =====================================================================
// pre0[d][t][b][r] = x[t,b,:] @ w_ih_l0[d].T + b_l0[d]   (fp32 out)
// =====================================================================
__global__ __launch_bounds__(256) void pre0_kernel(
    const float* __restrict__ x, const float* __restrict__ wih0,
    const float* __restrict__ b0, float* __restrict__ pre0)
{
    int bid = blockIdx.x;
    int d = bid / 800; int rem = bid % 800;
    int rc = rem / 8, tc = rem % 8;
    int rbase = rc * 32, tbase = tc * 32;
    __shared__ float Wc[32][DIN];
    __shared__ float bias[32];
    __shared__ float xb[BATCH][DIN];
    int tid = threadIdx.x;
    for (int idx = tid; idx < 32 * DIN; idx += 256) {
        int rl = idx / DIN, k = idx % DIN;
        Wc[rl][k] = wih0[((size_t)d * NGATE + rbase + rl) * DIN + k];
    }
    if (tid < 32) bias[tid] = b0[d * NGATE + rbase + tid];
    __syncthreads();
    for (int tt = 0; tt < 32; ++tt) {
        int t = tbase + tt;
        for (int idx = tid; idx < BATCH * DIN; idx += 256) {
            int bb = idx / DIN, k = idx % DIN;
            xb[bb][k] = x[((size_t)bb * L_SEQ + t) * DIN + k];
        }
        __syncthreads();
        for (int o = tid; o < 512; o += 256) {
            int bb = o >> 5, rl = o & 31;
            float s = bias[rl];
            #pragma unroll 6
            for (int k = 0; k < DIN; ++k) s += xb[bb][k] * Wc[rl][k];
            pre0[((size_t)(d * L_SEQ + t) * BATCH + bb) * NGATE + rbase + rl] = s;
        }
        __syncthreads();
    }
}

// =====================================================================
// Persistent bidirectional LSTM scan — BARRIER-FREE dataflow version.
// Each stored h word carries a 2-bit slot-parity tag in the 2 LSBs of the
// lo residual (bits 17:16). Consumers retry-load their 52 h words until
// every tag matches the slot parity; no flags, no global barrier, no
// fences, no post-fuse drain. exch is step-parity double-buffered so a
// single __syncthreads per step suffices. Slots are write-once (archive),
// so fast blocks can never corrupt data for slow ones.
// Poison 0xAAAA has tag 0b10 -> never matches (tags are only 0/1);
// memset-zero boundary slots have tag 0 == parity of slot 0/256.
// =====================================================================
__global__ __launch_bounds__(256, 1) void scan_kernel(
    const unsigned short* __restrict__ wpackH,
    const unsigned short* __restrict__ wpackL,
    const float* __restrict__ pre,              // [d][t][b][3200] fp32
    uint32_t* hFP, uint32_t* hBP)               // packed h archives [257][16][800]
{
    __shared__ __align__(16) unsigned short wldsH[25600];   // 51.2 KB
    __shared__ __align__(16) unsigned short wldsL[25600];   // 51.2 KB
    __shared__ __align__(16) float exch[2][2][2][64][4];    // [par][nt][kh][lane][reg]
    __shared__ float cbuf[128];
    int tid = threadIdx.x;
    int bid = blockIdx.x;
    int d = bid / 100, jc = bid % 100;

    {   // load weight fragments once
        const short8* sh = (const short8*)wpackH + ((size_t)d * 100 + jc) * 3200;
        const short8* sl = (const short8*)wpackL + ((size_t)d * 100 + jc) * 3200;
        short8* dh = (short8*)wldsH;
        short8* dl = (short8*)wldsL;
        for (int i = tid; i < 3200; i += 256) { dh[i] = sh[i]; dl[i] = sl[i]; }
    }
    if (tid < 128) cbuf[tid] = 0.0f;
    __syncthreads();

    int lane = tid & 63, w = tid >> 6;
    int nt = w & 1, kh = w >> 1;
    int kkS = kh ? 13 : 0;
    int cnt = 13 - kh;              // 13 (kh=0) or 12 (kh=1) kk groups
    int bA = lane & 15, q = lane >> 4;

    // fuse-phase indices (waves 0,1)
    int fb = (tid >> 3) & 15, fj = tid & 7;

    uint32_t* hOutP = d ? hBP : hFP;
    const uint32_t* hInP = d ? hBP : hFP;
    constexpr unsigned long long TAGMASK = 0x0003000000030000ull;

    for (int s = 0; s < L_SEQ; ++s) {
        int t = d ? (L_SEQ - 1 - s) : s;
        int islot = d ? (t + 1) : t;
        const uint32_t* hrow = hInP + (size_t)islot * HSLOT + bA * HID;
        unsigned long long tg64 = ((unsigned long long)(islot & 1) << 16)
                                | ((unsigned long long)(islot & 1) << 48);

        // ---- prefetch pre gate values (independent of h; L2-cached) ----
        float pv[4];
        if (tid < 128) {
            const float* pp = pre + ((size_t)(d * L_SEQ + t) * BATCH + fb) * NGATE
                            + jc * 8 + fj;
            #pragma unroll
            for (int gate = 0; gate < 4; ++gate) pv[gate] = pp[gate * 800];
        }

        // ---- retry-load all 52 h words until every tag is fresh ----
        unsigned long long pk[13][4];
        bool ready;
        do {
            #pragma unroll
            for (int i = 0; i < 13; ++i) {
                if (i < cnt) {
                    int k0 = (kkS + i) * 32 + q * 8;
                    #pragma unroll
                    for (int j = 0; j < 4; ++j)
                        pk[i][j] = __hip_atomic_load(
                            (const unsigned long long*)(hrow + k0 + 2 * j),
                            __ATOMIC_RELAXED, __HIP_MEMORY_SCOPE_AGENT);
                }
            }
            unsigned long long bad = 0;
            #pragma unroll
            for (int i = 0; i < 13; ++i) {
                if (i < cnt) {
                    #pragma unroll
                    for (int j = 0; j < 4; ++j)
                        bad |= (pk[i][j] ^ tg64) & TAGMASK;
                }
            }
            ready = __all(bad == 0ull);
        } while (!ready);

        // ---- unpack + MFMA (dual accumulator) ----
        floatx4 acc0 = {0.f, 0.f, 0.f, 0.f};
        floatx4 acc1 = {0.f, 0.f, 0.f, 0.f};
        #pragma unroll
        for (int i = 0; i < 13; ++i) {
            if (i < cnt) {
                int kk = kkS + i;
                short8 ah, al;
                #pragma unroll
                for (int j = 0; j < 4; ++j) {
                    unsigned long long u = pk[i][j];
                    ah[2 * j]     = (short)(u & 0xffffull);
                    al[2 * j]     = (short)((u >> 16) & 0xffffull);
                    ah[2 * j + 1] = (short)((u >> 32) & 0xffffull);
                    al[2 * j + 1] = (short)(u >> 48);
                }
                short8 bh = ((const short8*)wldsH)[(nt * 25 + kk) * 64 + lane];
                short8 bl = ((const short8*)wldsL)[(nt * 25 + kk) * 64 + lane];
                acc0 = __builtin_amdgcn_mfma_f32_16x16x32_bf16(ah, bh, acc0, 0, 0, 0);
                acc1 = __builtin_amdgcn_mfma_f32_16x16x32_bf16(ah, bl, acc1, 0, 0, 0);
                acc1 = __builtin_amdgcn_mfma_f32_16x16x32_bf16(al, bh, acc1, 0, 0, 0);
            }
        }
        floatx4 acc = acc0 + acc1;
        int p = s & 1;
        *(floatx4*)&exch[p][nt][kh][lane][0] = acc;
        __syncthreads();     // ONE barrier per step (also drains prior-step stores)

        if (tid < 128) {
            float G[4];
            #pragma unroll
            for (int gate = 0; gate < 4; ++gate) {
                int lr = gate * 8 + fj;
                int nt2 = lr >> 4, n = lr & 15;
                int ln = ((fb >> 2) << 4) | n;
                int rg = fb & 3;
                G[gate] = exch[p][nt2][0][ln][rg] + exch[p][nt2][1][ln][rg] + pv[gate];
            }
            float i_ = sigf(G[0]), f_ = sigf(G[1]);
            float g_ = tanhfast(G[2]), o_ = sigf(G[3]);
            float c = f_ * cbuf[tid] + i_ * g_;
            cbuf[tid] = c;
            float h = o_ * tanhfast(c);
            int oslot = d ? t : (t + 1);
            size_t oidx = (size_t)oslot * HSLOT + fb * HID + jc * 8 + fj;
            unsigned short hh = f2bf(h);
            unsigned short lo = f2bf(h - bf2f(hh));
            lo = (unsigned short)((lo & 0xFFFCu) | (unsigned int)(oslot & 1));
            uint32_t pko = (uint32_t)hh | ((uint32_t)lo << 16);
            __hip_atomic_store(&hOutP[oidx], pko, __ATOMIC_RELAXED,
                               __HIP_MEMORY_SCOPE_AGENT);
        }
        // NO trailing syncthreads: exch is double-buffered; h-store ACKs
        // overlap the next step's retry-load phase.
    }
}

// =====================================================================
// pre1[d][t][b][r] = concat(h1f[t], h1b[t]) @ w_ih_l1[d].T + b_l1[d]  (fp32)
// split-precision 64x64-tile MFMA GEMM: M=4096 (t,b), N=3200, K=1600.
// (lo words carry 2 stolen tag bits — negligible, not masked)
// =====================================================================
__global__ __launch_bounds__(256, 1) void gemm_pre1_kernel(
    const uint32_t* __restrict__ hFP, const uint32_t* __restrict__ hBP,
    const unsigned short* __restrict__ wih1H, const unsigned short* __restrict__ wih1L,
    const float* __restrict__ b1, float* __restrict__ pre1)
{
    int bid = blockIdx.x;
    int d = bid / 3200; int rst = bid % 3200;
    int mblk = rst / 50, nblk = rst % 50;
    __shared__ __align__(16) unsigned short AslH[64][40];
    __shared__ __align__(16) unsigned short AslL[64][40];
    __shared__ __align__(16) unsigned short BslH[64][40];
    __shared__ __align__(16) unsigned short BslL[64][40];
    int tid = threadIdx.x, lane = tid & 63, w = tid >> 6;
    int wm = w >> 1, wn = w & 1;
    floatx4 acc[2][2] = {};
    int row = tid >> 2, ch = tid & 3;
    int m_row = mblk * 64 + row;
    int t = m_row >> 4, bb = m_row & 15;
    int la = lane & 15, q8 = (lane >> 4) * 8;

    for (int kk = 0; kk < 50; ++kk) {
        int k0 = kk * 32 + ch * 8;
        size_t aoff = (kk < 25)
            ? ((size_t)(t + 1) * HSLOT + bb * HID + k0)
            : ((size_t)t * HSLOT + bb * HID + (k0 - 800));
        const uint32_t* ap = ((kk < 25) ? hFP : hBP) + aoff;
        uint4 p0 = *(const uint4*)ap;
        uint4 p1 = *(const uint4*)(ap + 4);
        short8 ah, al;
        ah[0]=(short)(p0.x&0xffffu); al[0]=(short)(p0.x>>16);
        ah[1]=(short)(p0.y&0xffffu); al[1]=(short)(p0.y>>16);
        ah[2]=(short)(p0.z&0xffffu); al[2]=(short)(p0.z>>16);
        ah[3]=(short)(p0.w&0xffffu); al[3]=(short)(p0.w>>16);
        ah[4]=(short)(p1.x&0xffffu); al[4]=(short)(p1.x>>16);
        ah[5]=(short)(p1.y&0xffffu); al[5]=(short)(p1.y>>16);
        ah[6]=(short)(p1.z&0xffffu); al[6]=(short)(p1.z>>16);
        ah[7]=(short)(p1.w&0xffffu); al[7]=(short)(p1.w>>16);
        *(short8*)&AslH[row][ch * 8] = ah;
        *(short8*)&AslL[row][ch * 8] = al;
        size_t boff = ((size_t)d * NGATE + nblk * 64 + row) * 1600 + kk * 32 + ch * 8;
        *(short8*)&BslH[row][ch * 8] = *(const short8*)(wih1H + boff);
        *(short8*)&BslL[row][ch * 8] = *(const short8*)(wih1L + boff);
        __syncthreads();
        #pragma unroll
        for (int ms = 0; ms < 2; ++ms) {
            short8 fah = *(const short8*)&AslH[wm * 32 + ms * 16 + la][q8];
            short8 fal = *(const short8*)&AslL[wm * 32 + ms * 16 + la][q8];
            #pragma unroll
            for (int ns = 0; ns < 2; ++ns) {
                short8 fbh = *(const short8*)&BslH[wn * 32 + ns * 16 + la][q8];
                short8 fbl = *(const short8*)&BslL[wn * 32 + ns * 16 + la][q8];
                acc[ms][ns] = __builtin_amdgcn_mfma_f32_16x16x32_bf16(fah, fbh, acc[ms][ns], 0, 0, 0);
                acc[ms][ns] = __builtin_amdgcn_mfma_f32_16x16x32_bf16(fah, fbl, acc[ms][ns], 0, 0, 0);
                acc[ms][ns] = __builtin_amdgcn_mfma_f32_16x16x32_bf16(fal, fbh, acc[ms][ns], 0, 0, 0);
            }
        }
        __syncthreads();
    }
    #pragma unroll
    for (int ms = 0; ms < 2; ++ms)
        #pragma unroll
        for (int ns = 0; ns < 2; ++ns)
            #pragma unroll
            for (int rg = 0; rg < 4; ++rg) {
                int m = mblk * 64 + wm * 32 + ms * 16 + (lane >> 4) * 4 + rg;
                int t2 = m >> 4, b2 = m & 15;
                int r = nblk * 64 + wn * 32 + ns * 16 + (lane & 15);
                float val = acc[ms][ns][rg] + b1[d * NGATE + r];
                pre1[((size_t)(d * L_SEQ + t2) * BATCH + b2) * NGATE + r] = val;
            }
}

// =====================================================================
// Head: logits -> softmax -> torsion angles.  One block per t.
// =====================================================================
__global__ __launch_bounds__(256) void head_kernel(
    const uint32_t* __restrict__ h2FP, const uint32_t* __restrict__ h2BP,
    const float* __restrict__ wlin, const float* __restrict__ blin,
    const float* __restrict__ alphabet, float* __restrict__ ang)
{
    int t = blockIdx.x, tid = threadIdx.x;
    __shared__ float lg[BATCH * NALPHA];
    __shared__ float probs[BATCH * NALPHA];
    for (int i = tid; i < BATCH * NALPHA; i += 256) {
        int a = i % NALPHA, b = i / NALPHA;
        size_t fo = (size_t)(t + 1) * HSLOT + b * HID;
        size_t bo = (size_t)t * HSLOT + b * HID;
        const float* wa = wlin + (size_t)a * 1600;
        float s = blin[a];
        #pragma unroll 4
        for (int k = 0; k < HID; ++k) {
            uint32_t uf = h2FP[fo + k], ub = h2BP[bo + k];
            float hf = bf2f((unsigned short)uf) + bf2f((unsigned short)(uf >> 16));
            float hb = bf2f((unsigned short)ub) + bf2f((unsigned short)(ub >> 16));
            s += hf * wa[k] + hb * wa[800 + k];
        }
        lg[b * NALPHA + a] = s;
    }
    __syncthreads();
    if (tid < BATCH) {
        int b = tid;
        float mx = -1e30f;
        for (int a = 0; a < NALPHA; ++a) mx = fmaxf(mx, lg[b * NALPHA + a]);
        float sum = 0.f;
        for (int a = 0; a < NALPHA; ++a) {
            float e = __expf(lg[b * NALPHA + a] - mx);
            probs[b * NALPHA + a] = e; sum += e;
        }
        float inv = 1.0f / sum;
        for (int a = 0; a < NALPHA; ++a) probs[b * NALPHA + a] *= inv;
    }
    __syncthreads();
    if (tid < BATCH * 3) {
        int b = tid / 3, i = tid % 3;
        float ss = 0.f, cc = 0.f;
        for (int a = 0; a < NALPHA; ++a) {
            float al = alphabet[a * 3 + i], p = probs[b * NALPHA + a];
            ss += p * sinf(al); cc += p * cosf(al);
        }
        ang[((size_t)t * BATCH + b) * 3 + i] = atan2f(ss, cc);
    }
}

// =====================================================================
// Sequential NeRF coordinate chain. One block; lane b handles batch b.
// =====================================================================
__global__ __launch_bounds__(64) void coords_kernel(
    const float* __restrict__ ang, float* __restrict__ out)
{
    int b = threadIdx.x;
    if (b >= BATCH) return;
    const float LENS[3] = {145.801f, 152.326f, 132.868f};
    const float ANGS[3] = {2.124f, 1.941f, 2.028f};
    float Ax = 0.f, Ay = 0.f, Az = 1.f;
    float Bx = 0.f, By = 1.f, Bz = 0.f;
    float Cx = 1.f, Cy = 0.f, Cz = 0.f;
    out[((size_t)0 * BATCH + b) * 3 + 0] = 0.f; out[((size_t)0 * BATCH + b) * 3 + 1] = 0.f; out[((size_t)0 * BATCH + b) * 3 + 2] = 1.f;
    out[((size_t)1 * BATCH + b) * 3 + 0] = 0.f; out[((size_t)1 * BATCH + b) * 3 + 1] = 1.f; out[((size_t)1 * BATCH + b) * 3 + 2] = 0.f;
    out[((size_t)2 * BATCH + b) * 3 + 0] = 1.f; out[((size_t)2 * BATCH + b) * 3 + 1] = 0.f; out[((size_t)2 * BATCH + b) * 3 + 2] = 0.f;
    for (int t = 0; t < L_SEQ; ++t) {
        #pragma unroll
        for (int i = 0; i < 3; ++i) {
            float P = ang[((size_t)t * BATCH + b) * 3 + i];
            float R = LENS[i], T = ANGS[i];
            float sT = sinf(T);
            float D2x = -R * cosf(T);
            float D2y = R * cosf(P) * sT;
            float D2z = R * sinf(P) * sT;
            float bx = Cx - Bx, by = Cy - By, bz = Cz - Bz;
            float binv = 1.0f / sqrtf(bx * bx + by * by + bz * bz);
            bx *= binv; by *= binv; bz *= binv;
            float ux = Bx - Ax, uy = By - Ay, uz = Bz - Az;
            float nx = uy * bz - uz * by;
            float ny = uz * bx - ux * bz;
            float nz = ux * by - uy * bx;
            float ninv = 1.0f / sqrtf(nx * nx + ny * ny + nz * nz);
            nx *= ninv; ny *= ninv; nz *= ninv;
            float cxx = ny * bz - nz * by;
            float cxy = nz * bx - nx * bz;
            float cxz = nx * by - ny * bx;
            float Dx = bx * D2x + cxx * D2y + nx * D2z + Cx;
            float Dy = by * D2x + cxy * D2y + ny * D2z + Cy;
            float Dz = bz * D2x + cxz * D2y + nz * D2z + Cz;
            size_t orow = 3 + (size_t)t * 3 + i;
            out[(orow * BATCH + b) * 3 + 0] = Dx;
            out[(orow * BATCH + b) * 3 + 1] = Dy;
            out[(orow * BATCH + b) * 3 + 2] = Dz;
            Ax = Bx; Ay = By; Az = Bz;
            Bx = Cx; By = Cy; Bz = Cz;
            Cx = Dx; Cy = Dy; Cz = Dz;
        }
    }
}

// =====================================================================
extern "C" void kernel_launch(void* const* d_in, const int* in_sizes, int n_in,
                              void* d_out, int out_size, void* d_ws, size_t ws_size,
                              hipStream_t stream)
{
    const float* x       = (const float*)d_in[0];
    const float* w_ih_l0 = (const float*)d_in[1];
    const float* w_hh_l0 = (const float*)d_in[2];
    const float* b_l0    = (const float*)d_in[3];
    const float* w_ih_l1 = (const float*)d_in[4];
    const float* w_hh_l1 = (const float*)d_in[5];
    const float* b_l1    = (const float*)d_in[6];
    const float* w_lin   = (const float*)d_in[7];
    const float* b_lin   = (const float*)d_in[8];
    const float* alphabet= (const float*)d_in[9];
    (void)in_sizes; (void)n_in; (void)out_size; (void)ws_size;

    char* ws = (char*)d_ws;
    unsigned short* whhHi   = (unsigned short*)(ws + OFF_WHH_HI);
    unsigned short* whhLo   = (unsigned short*)(ws + OFF_WHH_LO);
    unsigned short* wih1Hi  = (unsigned short*)(ws + OFF_WIH1_HI);
    unsigned short* wih1Lo  = (unsigned short*)(ws + OFF_WIH1_LO);
    float*          pre     = (float*)(ws + OFF_PRE);       // pre0 then pre1 (aliased)
    uint32_t*       hFP     = (uint32_t*)(ws + OFF_H + 0 * SZ_HP);
    uint32_t*       hBP     = (uint32_t*)(ws + OFF_H + 1 * SZ_HP);
    uint32_t*       h2FP    = (uint32_t*)(ws + OFF_H + 2 * SZ_HP);
    uint32_t*       h2BP    = (uint32_t*)(ws + OFF_H + 3 * SZ_HP);
    float*          angbuf  = (float*)(ws + OFF_ANG);

    // zero boundary h slots (slot 0 for F bufs, slot 256 for B bufs);
    // zero word => tag bits 00 == parity of slot 0 / slot 256.
    const size_t slotB = (size_t)HSLOT * 4;
    hipMemsetAsync((char*)hFP, 0, slotB, stream);
    hipMemsetAsync((char*)hBP + 256 * slotB, 0, slotB, stream);
    hipMemsetAsync((char*)h2FP, 0, slotB, stream);
    hipMemsetAsync((char*)h2BP + 256 * slotB, 0, slotB, stream);

    pack_whh_kernel<<<5000, 256, 0, stream>>>(w_hh_l0, w_hh_l1, whhHi, whhLo);
    conv_wih1_kernel<<<5000, 256, 0, stream>>>(w_ih_l1, wih1Hi, wih1Lo);
    pre0_kernel<<<1600, 256, 0, stream>>>(x, w_ih_l0, b_l0, pre);

    // layer 0 bidirectional scan (barrier-free dataflow)
    scan_kernel<<<NBLK_SCAN, 256, 0, stream>>>(whhHi, whhLo, pre, hFP, hBP);
    // layer 1 input projection (overwrites pre in place: pre0 dead, pre1 live)
    gemm_pre1_kernel<<<6400, 256, 0, stream>>>(hFP, hBP, wih1Hi, wih1Lo, b_l1, pre);
    // layer 1 bidirectional scan
    constexpr size_t LOFF = SZ_WHH_L / 2;  // ushort elements per layer
    scan_kernel<<<NBLK_SCAN, 256, 0, stream>>>(whhHi + LOFF, whhLo + LOFF, pre,
                                               h2FP, h2BP);

    head_kernel<<<L_SEQ, 256, 0, stream>>>(h2FP, h2BP, w_lin, b_lin, alphabet, angbuf);
    coords_kernel<<<1, 64, 0, stream>>>(angbuf, (float*)d_out);
}

// Round 7
// 5378.179 us; speedup vs baseline: 1.4727x; 1.4727x over previous
//
#include <hip/hip_runtime.h>
#include <stdint.h>

typedef __attribute__((ext_vector_type(8))) short short8;
typedef __attribute__((ext_vector_type(4))) float floatx4;

#define DEVINL __device__ __forceinline__

DEVINL unsigned short f2bf(float f) {
    unsigned int u = __float_as_uint(f);
    u += 0x7FFFu + ((u >> 16) & 1u);
    return (unsigned short)(u >> 16);
}
DEVINL float bf2f(unsigned short h) {
    return __uint_as_float(((unsigned int)h) << 16);
}
DEVINL float sigf(float x)     { return 1.0f / (1.0f + __expf(-x)); }
DEVINL float tanhfast(float x) { return 2.0f / (1.0f + __expf(-2.0f * x)) - 1.0f; }

// ---------------- problem constants ----------------
constexpr int L_SEQ = 256, BATCH = 16, HID = 800, NGATE = 3200, DIN = 42, NALPHA = 20;
constexpr int HSLOT = BATCH * HID;          // 12800 elements per time slot
constexpr int NBLK_SCAN = 200;              // 2 dirs x 100 j-chunks (8 hidden units each)
constexpr int FLAG_STRIDE = 32;             // u32s: one flag per 128-B cacheline

// ---------------- workspace layout (bytes) ----------------
constexpr size_t OFF_FLAGS   = 0;                                   // 128 KB padded flags
constexpr size_t SZ_FLAGS    = 131072;
constexpr size_t SZ_WHH_L    = 10240000;                            // per layer: 2*3200*800*2B
constexpr size_t OFF_WHH_HI  = SZ_FLAGS;                            // 2 layers
constexpr size_t OFF_WHH_LO  = OFF_WHH_HI + 2 * SZ_WHH_L;
constexpr size_t SZ_WIH1     = 20480000;                            // 2*3200*1600*2B
constexpr size_t OFF_WIH1_HI = OFF_WHH_LO + 2 * SZ_WHH_L;
constexpr size_t OFF_WIH1_LO = OFF_WIH1_HI + SZ_WIH1;
constexpr size_t OFF_PRE     = OFF_WIH1_LO + SZ_WIH1;               // fp32, shared pre0/pre1
constexpr size_t SZ_PRE      = (size_t)2 * L_SEQ * BATCH * NGATE * 4;  // 104,857,600
constexpr size_t SZ_HP       = (size_t)257 * HSLOT * 4;             // 13,158,400 per packed buf
constexpr size_t OFF_H       = OFF_PRE + SZ_PRE;                    // 4 bufs: F, B, 2F, 2B
constexpr size_t OFF_ANG     = OFF_H + 4 * SZ_HP;                   // 256*16*3 fp32
// total ~228.6 MiB

// =====================================================================
// Pack W_hh (fp32 [2][3200][800]) into hi/lo MFMA B-fragment streams.
// =====================================================================
__global__ __launch_bounds__(256) void pack_whh_kernel(
    const float* __restrict__ w0, const float* __restrict__ w1,
    unsigned short* __restrict__ hi, unsigned short* __restrict__ lo)
{
    size_t g = (size_t)blockIdx.x * 256 + threadIdx.x;   // 1,280,000 total
    if (g >= 1280000) return;
    int l = (int)(g & 63);
    size_t gg = g >> 6;                                   // 20000 fragment ids
    int kk = (int)(gg % 25); gg /= 25;
    int nt = (int)(gg % 2);  gg /= 2;
    int jc = (int)(gg % 100); gg /= 100;
    int d  = (int)(gg % 2);
    int layer = (int)(gg / 2);
    const float* W = layer ? w1 : w0;
    int lr = nt * 16 + (l & 15);
    int gate = lr >> 3, jj = lr & 7;
    int r  = gate * 800 + jc * 8 + jj;
    int k0 = kk * 32 + (l >> 4) * 8;
    const float* s = W + ((size_t)d * NGATE + r) * HID + k0;
    short8 vh, vl;
    #pragma unroll
    for (int j = 0; j < 8; ++j) {
        float w = s[j];
        unsigned short h = f2bf(w);
        vh[j] = (short)h;
        vl[j] = (short)f2bf(w - bf2f(h));
    }
    size_t idx = (size_t)layer * 640000 + ((size_t)d * 100 + jc) * 3200
               + (size_t)(nt * 25 + kk) * 64 + l;
    ((short8*)hi)[idx] = vh;
    ((short8*)lo)[idx] = vl;
}

// =====================================================================
// fp32 -> hi/lo bf16 conversion of w_ih_l1 (flat [2][3200][1600]).
// =====================================================================
__global__ __launch_bounds__(256) void conv_wih1_kernel(
    const float* __restrict__ w, unsigned short* __restrict__ hi,
    unsigned short* __restrict__ lo)
{
    size_t g = (size_t)blockIdx.x * 256 + threadIdx.x;   // 1,280,000 groups of 8
    if (g >= 1280000) return;
    const float* s = w + g * 8;
    short8 vh, vl;
    #pragma unroll
    for (int j = 0; j < 8; ++j) {
        float x = s[j];
        unsigned short h = f2bf(x);
        vh[j] = (short)h;
        vl[j] = (short)f2bf(x - bf2f(h));
    }
    ((short8*)hi)[g] = vh;
    ((short8*)lo)[g] = vl;
}

// =====================================================================
// pre0[d][t][b][r] = x[t,b,:] @ w_ih_l0[d].T + b_l0[d]   (fp32 out)
// =====================================================================
__global__ __launch_bounds__(256) void pre0_kernel(
    const float* __restrict__ x, const float* __restrict__ wih0,
    const float* __restrict__ b0, float* __restrict__ pre0)
{
    int bid = blockIdx.x;
    int d = bid / 800; int rem = bid % 800;
    int rc = rem / 8, tc = rem % 8;
    int rbase = rc * 32, tbase = tc * 32;
    __shared__ float Wc[32][DIN];
    __shared__ float bias[32];
    __shared__ float xb[BATCH][DIN];
    int tid = threadIdx.x;
    for (int idx = tid; idx < 32 * DIN; idx += 256) {
        int rl = idx / DIN, k = idx % DIN;
        Wc[rl][k] = wih0[((size_t)d * NGATE + rbase + rl) * DIN + k];
    }
    if (tid < 32) bias[tid] = b0[d * NGATE + rbase + tid];
    __syncthreads();
    for (int tt = 0; tt < 32; ++tt) {
        int t = tbase + tt;
        for (int idx = tid; idx < BATCH * DIN; idx += 256) {
            int bb = idx / DIN, k = idx % DIN;
            xb[bb][k] = x[((size_t)bb * L_SEQ + t) * DIN + k];
        }
        __syncthreads();
        for (int o = tid; o < 512; o += 256) {
            int bb = o >> 5, rl = o & 31;
            float s = bias[rl];
            #pragma unroll 6
            for (int k = 0; k < DIN; ++k) s += xb[bb][k] * Wc[rl][k];
            pre0[((size_t)(d * L_SEQ + t) * BATCH + bb) * NGATE + rbase + rl] = s;
        }
        __syncthreads();
    }
}

// Unpack one 4x-u64 group into hi/lo bf16 fragments.
DEVINL void unpack8(const unsigned long long (&u)[4], short8& ah, short8& al) {
    #pragma unroll
    for (int j = 0; j < 4; ++j) {
        unsigned long long x = u[j];
        ah[2 * j]     = (short)(x & 0xffffull);
        al[2 * j]     = (short)((x >> 16) & 0xffffull);
        ah[2 * j + 1] = (short)((x >> 32) & 0xffffull);
        al[2 * j + 1] = (short)(x >> 48);
    }
}

// Batched load (all CNT*4 u64 sc1 loads in flight) + split-MFMA over K-half.
template<int CNT, int KKS>
DEVINL floatx4 half_mfma(const uint32_t* __restrict__ hrow, int q,
                         const short8* __restrict__ wH,
                         const short8* __restrict__ wL,
                         int nt, int lane)
{
    unsigned long long pk[CNT][4];
    #pragma unroll
    for (int i = 0; i < CNT; ++i) {
        int k0 = (KKS + i) * 32 + q * 8;
        #pragma unroll
        for (int j = 0; j < 4; ++j)
            pk[i][j] = __hip_atomic_load(
                (const unsigned long long*)(hrow + k0 + 2 * j),
                __ATOMIC_RELAXED, __HIP_MEMORY_SCOPE_AGENT);
    }
    floatx4 a0 = {0.f, 0.f, 0.f, 0.f};
    floatx4 a1 = {0.f, 0.f, 0.f, 0.f};
    #pragma unroll
    for (int i = 0; i < CNT; ++i) {
        int kk = KKS + i;
        short8 ah, al;
        unpack8(pk[i], ah, al);
        short8 bh = wH[(nt * 25 + kk) * 64 + lane];
        short8 bl = wL[(nt * 25 + kk) * 64 + lane];
        a0 = __builtin_amdgcn_mfma_f32_16x16x32_bf16(ah, bh, a0, 0, 0, 0);
        a1 = __builtin_amdgcn_mfma_f32_16x16x32_bf16(ah, bl, a1, 0, 0, 0);
        a1 = __builtin_amdgcn_mfma_f32_16x16x32_bf16(al, bh, a1, 0, 0, 0);
    }
    return a0 + a1;
}

// =====================================================================
// Persistent bidirectional LSTM scan (split-precision bf16 hi/lo).
// Round-7 sync design:
//  - per-fuse-wave flags, padded one per 128-B line (no false sharing)
//  - fuse waves drain own sc1 h-stores via inline s_waitcnt vmcnt(0)
//    (no agent-release wbl2), then store flag value s+1
//  - ONE __syncthreads per step (exch step-parity double-buffered)
//  - wave 0 polls 200 padded flags; waves 1-3 spin on an LDS relay word
//  - h loads fully batched via template-unrolled half_mfma
// =====================================================================
__global__ __launch_bounds__(256, 1) void scan_kernel(
    const unsigned short* __restrict__ wpackH,
    const unsigned short* __restrict__ wpackL,
    const float* __restrict__ pre,              // [d][t][b][3200] fp32
    uint32_t* hFP, uint32_t* hBP,               // packed h archives [257][16][800]
    unsigned int* flags)                        // this launch: [2 dirs][200*32 u32]
{
    __shared__ __align__(16) unsigned short wldsH[25600];   // 51.2 KB
    __shared__ __align__(16) unsigned short wldsL[25600];   // 51.2 KB
    __shared__ __align__(16) float exch[2][2][2][64][4];    // [par][nt][kh][lane][reg]
    __shared__ float cbuf[128];
    __shared__ unsigned int step_ready;
    int tid = threadIdx.x;
    int bid = blockIdx.x;
    int d = bid / 100, jc = bid % 100;
    unsigned int* dirFlags = flags + (size_t)d * 200 * FLAG_STRIDE;

    {   // load weight fragments once
        const short8* sh = (const short8*)wpackH + ((size_t)d * 100 + jc) * 3200;
        const short8* sl = (const short8*)wpackL + ((size_t)d * 100 + jc) * 3200;
        short8* dh = (short8*)wldsH;
        short8* dl = (short8*)wldsL;
        for (int i = tid; i < 3200; i += 256) { dh[i] = sh[i]; dl[i] = sl[i]; }
    }
    if (tid < 128) cbuf[tid] = 0.0f;
    if (tid == 0) step_ready = 0u;
    __syncthreads();

    int lane = tid & 63, w = tid >> 6;
    int nt = w & 1, kh = w >> 1;
    int bA = lane & 15, q = lane >> 4;
    int fb = (tid >> 3) & 15, fj = tid & 7;     // fuse indices (tid<128)

    uint32_t* hOutP = d ? hBP : hFP;
    const uint32_t* hInP = d ? hBP : hFP;

    for (int s = 0; s < L_SEQ; ++s) {
        int t = d ? (L_SEQ - 1 - s) : s;
        int islot = d ? (t + 1) : t;
        const uint32_t* hrow = hInP + (size_t)islot * HSLOT + bA * HID;

        // prefetch pre gate values (independent of h) before waiting
        float pv[4];
        if (tid < 128) {
            const float* pp = pre + ((size_t)(d * L_SEQ + t) * BATCH + fb) * NGATE
                            + jc * 8 + fj;
            #pragma unroll
            for (int gate = 0; gate < 4; ++gate) pv[gate] = pp[gate * 800];
        }

        if (s > 0) {
            unsigned int need = (unsigned int)s;
            if (w == 0) {   // wave 0: poll all 200 padded flags in parallel
                bool ok;
                do {
                    unsigned v0 = __hip_atomic_load(&dirFlags[lane * FLAG_STRIDE],
                                    __ATOMIC_RELAXED, __HIP_MEMORY_SCOPE_AGENT);
                    unsigned v1 = __hip_atomic_load(&dirFlags[(lane + 64) * FLAG_STRIDE],
                                    __ATOMIC_RELAXED, __HIP_MEMORY_SCOPE_AGENT);
                    unsigned v2 = __hip_atomic_load(&dirFlags[(lane + 128) * FLAG_STRIDE],
                                    __ATOMIC_RELAXED, __HIP_MEMORY_SCOPE_AGENT);
                    unsigned v3 = (lane < 8)
                        ? __hip_atomic_load(&dirFlags[(lane + 192) * FLAG_STRIDE],
                                    __ATOMIC_RELAXED, __HIP_MEMORY_SCOPE_AGENT)
                        : 0xFFFFFFFFu;
                    ok = __all(v0 >= need && v1 >= need && v2 >= need && v3 >= need);
                } while (!ok);
                if (lane == 0)
                    __hip_atomic_store(&step_ready, need, __ATOMIC_RELAXED,
                                       __HIP_MEMORY_SCOPE_WORKGROUP);
            } else {        // waves 1-3: local LDS spin (no global traffic)
                while (__hip_atomic_load(&step_ready, __ATOMIC_RELAXED,
                                         __HIP_MEMORY_SCOPE_WORKGROUP) < need) {}
            }
        }
        asm volatile("" ::: "memory");   // keep h loads below the wait

        floatx4 acc = (kh == 0)
            ? half_mfma<13, 0>(hrow, q, (const short8*)wldsH, (const short8*)wldsL, nt, lane)
            : half_mfma<12, 13>(hrow, q, (const short8*)wldsH, (const short8*)wldsL, nt, lane);

        int p = s & 1;
        *(floatx4*)&exch[p][nt][kh][lane][0] = acc;
        __syncthreads();     // the ONE barrier per step

        if (tid < 128) {
            float G[4];
            #pragma unroll
            for (int gate = 0; gate < 4; ++gate) {
                int lr = gate * 8 + fj;
                int nt2 = lr >> 4, n = lr & 15;
                int ln = ((fb >> 2) << 4) | n;
                int rg = fb & 3;
                G[gate] = exch[p][nt2][0][ln][rg] + exch[p][nt2][1][ln][rg] + pv[gate];
            }
            float i_ = sigf(G[0]), f_ = sigf(G[1]);
            float g_ = tanhfast(G[2]), o_ = sigf(G[3]);
            float c = f_ * cbuf[tid] + i_ * g_;
            cbuf[tid] = c;
            float h = o_ * tanhfast(c);
            int oslot = d ? t : (t + 1);
            size_t oidx = (size_t)oslot * HSLOT + fb * HID + jc * 8 + fj;
            unsigned short hh = f2bf(h);
            uint32_t pko = (uint32_t)hh
                         | ((uint32_t)f2bf(h - bf2f(hh)) << 16);
            __hip_atomic_store(&hOutP[oidx], pko, __ATOMIC_RELAXED,
                               __HIP_MEMORY_SCOPE_AGENT);
            // drain only THIS wave's sc1 stores (no wbl2), then publish flag
            asm volatile("s_waitcnt vmcnt(0)" ::: "memory");
            if (lane == 0)
                __hip_atomic_store(&dirFlags[(jc * 2 + w) * FLAG_STRIDE],
                                   (unsigned int)(s + 1),
                                   __ATOMIC_RELAXED, __HIP_MEMORY_SCOPE_AGENT);
        }
        // no trailing barrier: exch double-buffered; next-step barrier orders reuse
    }
}

// =====================================================================
// pre1[d][t][b][r] = concat(h1f[t], h1b[t]) @ w_ih_l1[d].T + b_l1[d]  (fp32)
// split-precision 64x64-tile MFMA GEMM: M=4096 (t,b), N=3200, K=1600.
// =====================================================================
__global__ __launch_bounds__(256, 1) void gemm_pre1_kernel(
    const uint32_t* __restrict__ hFP, const uint32_t* __restrict__ hBP,
    const unsigned short* __restrict__ wih1H, const unsigned short* __restrict__ wih1L,
    const float* __restrict__ b1, float* __restrict__ pre1)
{
    int bid = blockIdx.x;
    int d = bid / 3200; int rst = bid % 3200;
    int mblk = rst / 50, nblk = rst % 50;
    __shared__ __align__(16) unsigned short AslH[64][40];
    __shared__ __align__(16) unsigned short AslL[64][40];
    __shared__ __align__(16) unsigned short BslH[64][40];
    __shared__ __align__(16) unsigned short BslL[64][40];
    int tid = threadIdx.x, lane = tid & 63, w = tid >> 6;
    int wm = w >> 1, wn = w & 1;
    floatx4 acc[2][2] = {};
    int row = tid >> 2, ch = tid & 3;
    int m_row = mblk * 64 + row;
    int t = m_row >> 4, bb = m_row & 15;
    int la = lane & 15, q8 = (lane >> 4) * 8;

    for (int kk = 0; kk < 50; ++kk) {
        int k0 = kk * 32 + ch * 8;
        size_t aoff = (kk < 25)
            ? ((size_t)(t + 1) * HSLOT + bb * HID + k0)
            : ((size_t)t * HSLOT + bb * HID + (k0 - 800));
        const uint32_t* ap = ((kk < 25) ? hFP : hBP) + aoff;
        uint4 p0 = *(const uint4*)ap;
        uint4 p1 = *(const uint4*)(ap + 4);
        short8 ah, al;
        ah[0]=(short)(p0.x&0xffffu); al[0]=(short)(p0.x>>16);
        ah[1]=(short)(p0.y&0xffffu); al[1]=(short)(p0.y>>16);
        ah[2]=(short)(p0.z&0xffffu); al[2]=(short)(p0.z>>16);
        ah[3]=(short)(p0.w&0xffffu); al[3]=(short)(p0.w>>16);
        ah[4]=(short)(p1.x&0xffffu); al[4]=(short)(p1.x>>16);
        ah[5]=(short)(p1.y&0xffffu); al[5]=(short)(p1.y>>16);
        ah[6]=(short)(p1.z&0xffffu); al[6]=(short)(p1.z>>16);
        ah[7]=(short)(p1.w&0xffffu); al[7]=(short)(p1.w>>16);
        *(short8*)&AslH[row][ch * 8] = ah;
        *(short8*)&AslL[row][ch * 8] = al;
        size_t boff = ((size_t)d * NGATE + nblk * 64 + row) * 1600 + kk * 32 + ch * 8;
        *(short8*)&BslH[row][ch * 8] = *(const short8*)(wih1H + boff);
        *(short8*)&BslL[row][ch * 8] = *(const short8*)(wih1L + boff);
        __syncthreads();
        #pragma unroll
        for (int ms = 0; ms < 2; ++ms) {
            short8 fah = *(const short8*)&AslH[wm * 32 + ms * 16 + la][q8];
            short8 fal = *(const short8*)&AslL[wm * 32 + ms * 16 + la][q8];
            #pragma unroll
            for (int ns = 0; ns < 2; ++ns) {
                short8 fbh = *(const short8*)&BslH[wn * 32 + ns * 16 + la][q8];
                short8 fbl = *(const short8*)&BslL[wn * 32 + ns * 16 + la][q8];
                acc[ms][ns] = __builtin_amdgcn_mfma_f32_16x16x32_bf16(fah, fbh, acc[ms][ns], 0, 0, 0);
                acc[ms][ns] = __builtin_amdgcn_mfma_f32_16x16x32_bf16(fah, fbl, acc[ms][ns], 0, 0, 0);
                acc[ms][ns] = __builtin_amdgcn_mfma_f32_16x16x32_bf16(fal, fbh, acc[ms][ns], 0, 0, 0);
            }
        }
        __syncthreads();
    }
    #pragma unroll
    for (int ms = 0; ms < 2; ++ms)
        #pragma unroll
        for (int ns = 0; ns < 2; ++ns)
            #pragma unroll
            for (int rg = 0; rg < 4; ++rg) {
                int m = mblk * 64 + wm * 32 + ms * 16 + (lane >> 4) * 4 + rg;
                int t2 = m >> 4, b2 = m & 15;
                int r = nblk * 64 + wn * 32 + ns * 16 + (lane & 15);
                float val = acc[ms][ns][rg] + b1[d * NGATE + r];
                pre1[((size_t)(d * L_SEQ + t2) * BATCH + b2) * NGATE + r] = val;
            }
}

// =====================================================================
// Head: logits -> softmax -> torsion angles.  One block per t.
// =====================================================================
__global__ __launch_bounds__(256) void head_kernel(
    const uint32_t* __restrict__ h2FP, const uint32_t* __restrict__ h2BP,
    const float* __restrict__ wlin, const float* __restrict__ blin,
    const float* __restrict__ alphabet, float* __restrict__ ang)
{
    int t = blockIdx.x, tid = threadIdx.x;
    __shared__ float lg[BATCH * NALPHA];
    __shared__ float probs[BATCH * NALPHA];
    for (int i = tid; i < BATCH * NALPHA; i += 256) {
        int a = i % NALPHA, b = i / NALPHA;
        size_t fo = (size_t)(t + 1) * HSLOT + b * HID;
        size_t bo = (size_t)t * HSLOT + b * HID;
        const float* wa = wlin + (size_t)a * 1600;
        float s = blin[a];
        #pragma unroll 4
        for (int k = 0; k < HID; ++k) {
            uint32_t uf = h2FP[fo + k], ub = h2BP[bo + k];
            float hf = bf2f((unsigned short)uf) + bf2f((unsigned short)(uf >> 16));
            float hb = bf2f((unsigned short)ub) + bf2f((unsigned short)(ub >> 16));
            s += hf * wa[k] + hb * wa[800 + k];
        }
        lg[b * NALPHA + a] = s;
    }
    __syncthreads();
    if (tid < BATCH) {
        int b = tid;
        float mx = -1e30f;
        for (int a = 0; a < NALPHA; ++a) mx = fmaxf(mx, lg[b * NALPHA + a]);
        float sum = 0.f;
        for (int a = 0; a < NALPHA; ++a) {
            float e = __expf(lg[b * NALPHA + a] - mx);
            probs[b * NALPHA + a] = e; sum += e;
        }
        float inv = 1.0f / sum;
        for (int a = 0; a < NALPHA; ++a) probs[b * NALPHA + a] *= inv;
    }
    __syncthreads();
    if (tid < BATCH * 3) {
        int b = tid / 3, i = tid % 3;
        float ss = 0.f, cc = 0.f;
        for (int a = 0; a < NALPHA; ++a) {
            float al = alphabet[a * 3 + i], p = probs[b * NALPHA + a];
            ss += p * sinf(al); cc += p * cosf(al);
        }
        ang[((size_t)t * BATCH + b) * 3 + i] = atan2f(ss, cc);
    }
}

// =====================================================================
// Sequential NeRF coordinate chain. One block; lane b handles batch b.
// =====================================================================
__global__ __launch_bounds__(64) void coords_kernel(
    const float* __restrict__ ang, float* __restrict__ out)
{
    int b = threadIdx.x;
    if (b >= BATCH) return;
    const float LENS[3] = {145.801f, 152.326f, 132.868f};
    const float ANGS[3] = {2.124f, 1.941f, 2.028f};
    float Ax = 0.f, Ay = 0.f, Az = 1.f;
    float Bx = 0.f, By = 1.f, Bz = 0.f;
    float Cx = 1.f, Cy = 0.f, Cz = 0.f;
    out[((size_t)0 * BATCH + b) * 3 + 0] = 0.f; out[((size_t)0 * BATCH + b) * 3 + 1] = 0.f; out[((size_t)0 * BATCH + b) * 3 + 2] = 1.f;
    out[((size_t)1 * BATCH + b) * 3 + 0] = 0.f; out[((size_t)1 * BATCH + b) * 3 + 1] = 1.f; out[((size_t)1 * BATCH + b) * 3 + 2] = 0.f;
    out[((size_t)2 * BATCH + b) * 3 + 0] = 1.f; out[((size_t)2 * BATCH + b) * 3 + 1] = 0.f; out[((size_t)2 * BATCH + b) * 3 + 2] = 0.f;
    for (int t = 0; t < L_SEQ; ++t) {
        #pragma unroll
        for (int i = 0; i < 3; ++i) {
            float P = ang[((size_t)t * BATCH + b) * 3 + i];
            float R = LENS[i], T = ANGS[i];
            float sT = sinf(T);
            float D2x = -R * cosf(T);
            float D2y = R * cosf(P) * sT;
            float D2z = R * sinf(P) * sT;
            float bx = Cx - Bx, by = Cy - By, bz = Cz - Bz;
            float binv = 1.0f / sqrtf(bx * bx + by * by + bz * bz);
            bx *= binv; by *= binv; bz *= binv;
            float ux = Bx - Ax, uy = By - Ay, uz = Bz - Az;
            float nx = uy * bz - uz * by;
            float ny = uz * bx - ux * bz;
            float nz = ux * by - uy * bx;
            float ninv = 1.0f / sqrtf(nx * nx + ny * ny + nz * nz);
            nx *= ninv; ny *= ninv; nz *= ninv;
            float cxx = ny * bz - nz * by;
            float cxy = nz * bx - nx * bz;
            float cxz = nx * by - ny * bx;
            float Dx = bx * D2x + cxx * D2y + nx * D2z + Cx;
            float Dy = by * D2x + cxy * D2y + ny * D2z + Cy;
            float Dz = bz * D2x + cxz * D2y + nz * D2z + Cz;
            size_t orow = 3 + (size_t)t * 3 + i;
            out[(orow * BATCH + b) * 3 + 0] = Dx;
            out[(orow * BATCH + b) * 3 + 1] = Dy;
            out[(orow * BATCH + b) * 3 + 2] = Dz;
            Ax = Bx; Ay = By; Az = Bz;
            Bx = Cx; By = Cy; Bz = Cz;
            Cx = Dx; Cy = Dy; Cz = Dz;
        }
    }
}

// =====================================================================
extern "C" void kernel_launch(void* const* d_in, const int* in_sizes, int n_in,
                              void* d_out, int out_size, void* d_ws, size_t ws_size,
                              hipStream_t stream)
{
    const float* x       = (const float*)d_in[0];
    const float* w_ih_l0 = (const float*)d_in[1];
    const float* w_hh_l0 = (const float*)d_in[2];
    const float* b_l0    = (const float*)d_in[3];
    const float* w_ih_l1 = (const float*)d_in[4];
    const float* w_hh_l1 = (const float*)d_in[5];
    const float* b_l1    = (const float*)d_in[6];
    const float* w_lin   = (const float*)d_in[7];
    const float* b_lin   = (const float*)d_in[8];
    const float* alphabet= (const float*)d_in[9];
    (void)in_sizes; (void)n_in; (void)out_size; (void)ws_size;

    char* ws = (char*)d_ws;
    unsigned int*   flags   = (unsigned int*)(ws + OFF_FLAGS);
    unsigned short* whhHi   = (unsigned short*)(ws + OFF_WHH_HI);
    unsigned short* whhLo   = (unsigned short*)(ws + OFF_WHH_LO);
    unsigned short* wih1Hi  = (unsigned short*)(ws + OFF_WIH1_HI);
    unsigned short* wih1Lo  = (unsigned short*)(ws + OFF_WIH1_LO);
    float*          pre     = (float*)(ws + OFF_PRE);       // pre0 then pre1 (aliased)
    uint32_t*       hFP     = (uint32_t*)(ws + OFF_H + 0 * SZ_HP);
    uint32_t*       hBP     = (uint32_t*)(ws + OFF_H + 1 * SZ_HP);
    uint32_t*       h2FP    = (uint32_t*)(ws + OFF_H + 2 * SZ_HP);
    uint32_t*       h2BP    = (uint32_t*)(ws + OFF_H + 3 * SZ_HP);
    float*          angbuf  = (float*)(ws + OFF_ANG);

    // zero flags (poison 0xAA would false-pass polls) + boundary h slots
    hipMemsetAsync(ws + OFF_FLAGS, 0, SZ_FLAGS, stream);
    const size_t slotB = (size_t)HSLOT * 4;
    hipMemsetAsync((char*)hFP, 0, slotB, stream);
    hipMemsetAsync((char*)hBP + 256 * slotB, 0, slotB, stream);
    hipMemsetAsync((char*)h2FP, 0, slotB, stream);
    hipMemsetAsync((char*)h2BP + 256 * slotB, 0, slotB, stream);

    pack_whh_kernel<<<5000, 256, 0, stream>>>(w_hh_l0, w_hh_l1, whhHi, whhLo);
    conv_wih1_kernel<<<5000, 256, 0, stream>>>(w_ih_l1, wih1Hi, wih1Lo);
    pre0_kernel<<<1600, 256, 0, stream>>>(x, w_ih_l0, b_l0, pre);

    // layer 0 bidirectional scan (flag region 0)
    scan_kernel<<<NBLK_SCAN, 256, 0, stream>>>(whhHi, whhLo, pre, hFP, hBP, flags);
    // layer 1 input projection (overwrites pre in place: pre0 dead, pre1 live)
    gemm_pre1_kernel<<<6400, 256, 0, stream>>>(hFP, hBP, wih1Hi, wih1Lo, b_l1, pre);
    // layer 1 bidirectional scan (flag region 1: 2*200*32 u32 later)
    constexpr size_t LOFF = SZ_WHH_L / 2;  // ushort elements per layer
    scan_kernel<<<NBLK_SCAN, 256, 0, stream>>>(whhHi + LOFF, whhLo + LOFF, pre,
                                               h2FP, h2BP, flags + 2 * 200 * FLAG_STRIDE);

    head_kernel<<<L_SEQ, 256, 0, stream>>>(h2FP, h2BP, w_lin, b_lin, alphabet, angbuf);
    coords_kernel<<<1, 64, 0, stream>>>(angbuf, (float*)d_out);
}

// Round 8
// 4228.394 us; speedup vs baseline: 1.8731x; 1.2719x over previous
//
#include <hip/hip_runtime.h>
#include <stdint.h>

typedef __attribute__((ext_vector_type(8))) short short8;
typedef __attribute__((ext_vector_type(4))) float floatx4;
typedef __attribute__((ext_vector_type(4))) unsigned int uintx4;

#define DEVINL __device__ __forceinline__

DEVINL unsigned short f2bf(float f) {
    unsigned int u = __float_as_uint(f);
    u += 0x7FFFu + ((u >> 16) & 1u);
    return (unsigned short)(u >> 16);
}
DEVINL float bf2f(unsigned short h) {
    return __uint_as_float(((unsigned int)h) << 16);
}
DEVINL float sigf(float x)     { return 1.0f / (1.0f + __expf(-x)); }
DEVINL float tanhfast(float x) { return 2.0f / (1.0f + __expf(-2.0f * x)) - 1.0f; }

// ---------------- problem constants ----------------
constexpr int L_SEQ = 256, BATCH = 16, HID = 800, NGATE = 3200, DIN = 42, NALPHA = 20;
constexpr int HSLOT = BATCH * HID;          // 12800 elements per time slot
constexpr int NBLK_SCAN = 200;              // 2 dirs x 100 j-chunks (8 hidden units each)
constexpr int FLAG_STRIDE = 32;             // u32s: one flag per 128-B cacheline

// ---------------- workspace layout (bytes) ----------------
constexpr size_t OFF_FLAGS   = 0;                                   // 128 KB padded flags
constexpr size_t SZ_FLAGS    = 131072;
constexpr size_t SZ_WHH_L    = 10240000;                            // per layer: 2*3200*800*2B
constexpr size_t OFF_WHH_HI  = SZ_FLAGS;                            // 2 layers
constexpr size_t OFF_WHH_LO  = OFF_WHH_HI + 2 * SZ_WHH_L;
constexpr size_t SZ_WIH1     = 20480000;                            // 2*3200*1600*2B
constexpr size_t OFF_WIH1_HI = OFF_WHH_LO + 2 * SZ_WHH_L;
constexpr size_t OFF_WIH1_LO = OFF_WIH1_HI + SZ_WIH1;
constexpr size_t OFF_PRE     = OFF_WIH1_LO + SZ_WIH1;               // fp32, shared pre0/pre1
constexpr size_t SZ_PRE      = (size_t)2 * L_SEQ * BATCH * NGATE * 4;  // 104,857,600
constexpr size_t SZ_HP       = (size_t)257 * HSLOT * 4;             // 13,158,400 per packed buf
constexpr size_t OFF_H       = OFF_PRE + SZ_PRE;                    // 4 bufs: F, B, 2F, 2B
constexpr size_t OFF_ANG     = OFF_H + 4 * SZ_HP;                   // 256*16*3 fp32
// total ~228.6 MiB

// =====================================================================
// Pack W_hh (fp32 [2][3200][800]) into hi/lo MFMA B-fragment streams.
// =====================================================================
__global__ __launch_bounds__(256) void pack_whh_kernel(
    const float* __restrict__ w0, const float* __restrict__ w1,
    unsigned short* __restrict__ hi, unsigned short* __restrict__ lo)
{
    size_t g = (size_t)blockIdx.x * 256 + threadIdx.x;   // 1,280,000 total
    if (g >= 1280000) return;
    int l = (int)(g & 63);
    size_t gg = g >> 6;                                   // 20000 fragment ids
    int kk = (int)(gg % 25); gg /= 25;
    int nt = (int)(gg % 2);  gg /= 2;
    int jc = (int)(gg % 100); gg /= 100;
    int d  = (int)(gg % 2);
    int layer = (int)(gg / 2);
    const float* W = layer ? w1 : w0;
    int lr = nt * 16 + (l & 15);
    int gate = lr >> 3, jj = lr & 7;
    int r  = gate * 800 + jc * 8 + jj;
    int k0 = kk * 32 + (l >> 4) * 8;
    const float* s = W + ((size_t)d * NGATE + r) * HID + k0;
    short8 vh, vl;
    #pragma unroll
    for (int j = 0; j < 8; ++j) {
        float w = s[j];
        unsigned short h = f2bf(w);
        vh[j] = (short)h;
        vl[j] = (short)f2bf(w - bf2f(h));
    }
    size_t idx = (size_t)layer * 640000 + ((size_t)d * 100 + jc) * 3200
               + (size_t)(nt * 25 + kk) * 64 + l;
    ((short8*)hi)[idx] = vh;
    ((short8*)lo)[idx] = vl;
}

// =====================================================================
// fp32 -> hi/lo bf16 conversion of w_ih_l1 (flat [2][3200][1600]).
// =====================================================================
__global__ __launch_bounds__(256) void conv_wih1_kernel(
    const float* __restrict__ w, unsigned short* __restrict__ hi,
    unsigned short* __restrict__ lo)
{
    size_t g = (size_t)blockIdx.x * 256 + threadIdx.x;   // 1,280,000 groups of 8
    if (g >= 1280000) return;
    const float* s = w + g * 8;
    short8 vh, vl;
    #pragma unroll
    for (int j = 0; j < 8; ++j) {
        float x = s[j];
        unsigned short h = f2bf(x);
        vh[j] = (short)h;
        vl[j] = (short)f2bf(x - bf2f(h));
    }
    ((short8*)hi)[g] = vh;
    ((short8*)lo)[g] = vl;
}

// =====================================================================
// pre0[d][t][b][r] = x[t,b,:] @ w_ih_l0[d].T + b_l0[d]   (fp32 out)
// =====================================================================
__global__ __launch_bounds__(256) void pre0_kernel(
    const float* __restrict__ x, const float* __restrict__ wih0,
    const float* __restrict__ b0, float* __restrict__ pre0)
{
    int bid = blockIdx.x;
    int d = bid / 800; int rem = bid % 800;
    int rc = rem / 8, tc = rem % 8;
    int rbase = rc * 32, tbase = tc * 32;
    __shared__ float Wc[32][DIN];
    __shared__ float bias[32];
    __shared__ float xb[BATCH][DIN];
    int tid = threadIdx.x;
    for (int idx = tid; idx < 32 * DIN; idx += 256) {
        int rl = idx / DIN, k = idx % DIN;
        Wc[rl][k] = wih0[((size_t)d * NGATE + rbase + rl) * DIN + k];
    }
    if (tid < 32) bias[tid] = b0[d * NGATE + rbase + tid];
    __syncthreads();
    for (int tt = 0; tt < 32; ++tt) {
        int t = tbase + tt;
        for (int idx = tid; idx < BATCH * DIN; idx += 256) {
            int bb = idx / DIN, k = idx % DIN;
            xb[bb][k] = x[((size_t)bb * L_SEQ + t) * DIN + k];
        }
        __syncthreads();
        for (int o = tid; o < 512; o += 256) {
            int bb = o >> 5, rl = o & 31;
            float s = bias[rl];
            #pragma unroll 6
            for (int k = 0; k < DIN; ++k) s += xb[bb][k] * Wc[rl][k];
            pre0[((size_t)(d * L_SEQ + t) * BATCH + bb) * NGATE + rbase + rl] = s;
        }
        __syncthreads();
    }
}

// =====================================================================
// Forced-batch system-scope loads: all dwordx4 loads issued in one asm
// block (single vmcnt wait). Early-clobber outputs prevent addr aliasing.
// =====================================================================
DEVINL void batch_load_26(const uint32_t* base, uintx4* pk) {
    asm volatile(
        "global_load_dwordx4 %0, %26, off sc0 sc1\n\t"
        "global_load_dwordx4 %1, %26, off offset:16 sc0 sc1\n\t"
        "global_load_dwordx4 %2, %26, off offset:128 sc0 sc1\n\t"
        "global_load_dwordx4 %3, %26, off offset:144 sc0 sc1\n\t"
        "global_load_dwordx4 %4, %26, off offset:256 sc0 sc1\n\t"
        "global_load_dwordx4 %5, %26, off offset:272 sc0 sc1\n\t"
        "global_load_dwordx4 %6, %26, off offset:384 sc0 sc1\n\t"
        "global_load_dwordx4 %7, %26, off offset:400 sc0 sc1\n\t"
        "global_load_dwordx4 %8, %26, off offset:512 sc0 sc1\n\t"
        "global_load_dwordx4 %9, %26, off offset:528 sc0 sc1\n\t"
        "global_load_dwordx4 %10, %26, off offset:640 sc0 sc1\n\t"
        "global_load_dwordx4 %11, %26, off offset:656 sc0 sc1\n\t"
        "global_load_dwordx4 %12, %26, off offset:768 sc0 sc1\n\t"
        "global_load_dwordx4 %13, %26, off offset:784 sc0 sc1\n\t"
        "global_load_dwordx4 %14, %26, off offset:896 sc0 sc1\n\t"
        "global_load_dwordx4 %15, %26, off offset:912 sc0 sc1\n\t"
        "global_load_dwordx4 %16, %26, off offset:1024 sc0 sc1\n\t"
        "global_load_dwordx4 %17, %26, off offset:1040 sc0 sc1\n\t"
        "global_load_dwordx4 %18, %26, off offset:1152 sc0 sc1\n\t"
        "global_load_dwordx4 %19, %26, off offset:1168 sc0 sc1\n\t"
        "global_load_dwordx4 %20, %26, off offset:1280 sc0 sc1\n\t"
        "global_load_dwordx4 %21, %26, off offset:1296 sc0 sc1\n\t"
        "global_load_dwordx4 %22, %26, off offset:1408 sc0 sc1\n\t"
        "global_load_dwordx4 %23, %26, off offset:1424 sc0 sc1\n\t"
        "global_load_dwordx4 %24, %26, off offset:1536 sc0 sc1\n\t"
        "global_load_dwordx4 %25, %26, off offset:1552 sc0 sc1\n\t"
        "s_waitcnt vmcnt(0)"
        : "=&v"(pk[0]), "=&v"(pk[1]), "=&v"(pk[2]), "=&v"(pk[3]),
          "=&v"(pk[4]), "=&v"(pk[5]), "=&v"(pk[6]), "=&v"(pk[7]),
          "=&v"(pk[8]), "=&v"(pk[9]), "=&v"(pk[10]), "=&v"(pk[11]),
          "=&v"(pk[12]), "=&v"(pk[13]), "=&v"(pk[14]), "=&v"(pk[15]),
          "=&v"(pk[16]), "=&v"(pk[17]), "=&v"(pk[18]), "=&v"(pk[19]),
          "=&v"(pk[20]), "=&v"(pk[21]), "=&v"(pk[22]), "=&v"(pk[23]),
          "=&v"(pk[24]), "=&v"(pk[25])
        : "v"(base)
        : "memory");
}

DEVINL void batch_load_24(const uint32_t* base, uintx4* pk) {
    asm volatile(
        "global_load_dwordx4 %0, %24, off sc0 sc1\n\t"
        "global_load_dwordx4 %1, %24, off offset:16 sc0 sc1\n\t"
        "global_load_dwordx4 %2, %24, off offset:128 sc0 sc1\n\t"
        "global_load_dwordx4 %3, %24, off offset:144 sc0 sc1\n\t"
        "global_load_dwordx4 %4, %24, off offset:256 sc0 sc1\n\t"
        "global_load_dwordx4 %5, %24, off offset:272 sc0 sc1\n\t"
        "global_load_dwordx4 %6, %24, off offset:384 sc0 sc1\n\t"
        "global_load_dwordx4 %7, %24, off offset:400 sc0 sc1\n\t"
        "global_load_dwordx4 %8, %24, off offset:512 sc0 sc1\n\t"
        "global_load_dwordx4 %9, %24, off offset:528 sc0 sc1\n\t"
        "global_load_dwordx4 %10, %24, off offset:640 sc0 sc1\n\t"
        "global_load_dwordx4 %11, %24, off offset:656 sc0 sc1\n\t"
        "global_load_dwordx4 %12, %24, off offset:768 sc0 sc1\n\t"
        "global_load_dwordx4 %13, %24, off offset:784 sc0 sc1\n\t"
        "global_load_dwordx4 %14, %24, off offset:896 sc0 sc1\n\t"
        "global_load_dwordx4 %15, %24, off offset:912 sc0 sc1\n\t"
        "global_load_dwordx4 %16, %24, off offset:1024 sc0 sc1\n\t"
        "global_load_dwordx4 %17, %24, off offset:1040 sc0 sc1\n\t"
        "global_load_dwordx4 %18, %24, off offset:1152 sc0 sc1\n\t"
        "global_load_dwordx4 %19, %24, off offset:1168 sc0 sc1\n\t"
        "global_load_dwordx4 %20, %24, off offset:1280 sc0 sc1\n\t"
        "global_load_dwordx4 %21, %24, off offset:1296 sc0 sc1\n\t"
        "global_load_dwordx4 %22, %24, off offset:1408 sc0 sc1\n\t"
        "global_load_dwordx4 %23, %24, off offset:1424 sc0 sc1\n\t"
        "s_waitcnt vmcnt(0)"
        : "=&v"(pk[0]), "=&v"(pk[1]), "=&v"(pk[2]), "=&v"(pk[3]),
          "=&v"(pk[4]), "=&v"(pk[5]), "=&v"(pk[6]), "=&v"(pk[7]),
          "=&v"(pk[8]), "=&v"(pk[9]), "=&v"(pk[10]), "=&v"(pk[11]),
          "=&v"(pk[12]), "=&v"(pk[13]), "=&v"(pk[14]), "=&v"(pk[15]),
          "=&v"(pk[16]), "=&v"(pk[17]), "=&v"(pk[18]), "=&v"(pk[19]),
          "=&v"(pk[20]), "=&v"(pk[21]), "=&v"(pk[22]), "=&v"(pk[23])
        : "v"(base)
        : "memory");
}

DEVINL void unpack_u44(uintx4 p0, uintx4 p1, short8& ah, short8& al) {
    ah[0]=(short)(p0.x&0xffffu); al[0]=(short)(p0.x>>16);
    ah[1]=(short)(p0.y&0xffffu); al[1]=(short)(p0.y>>16);
    ah[2]=(short)(p0.z&0xffffu); al[2]=(short)(p0.z>>16);
    ah[3]=(short)(p0.w&0xffffu); al[3]=(short)(p0.w>>16);
    ah[4]=(short)(p1.x&0xffffu); al[4]=(short)(p1.x>>16);
    ah[5]=(short)(p1.y&0xffffu); al[5]=(short)(p1.y>>16);
    ah[6]=(short)(p1.z&0xffffu); al[6]=(short)(p1.z>>16);
    ah[7]=(short)(p1.w&0xffffu); al[7]=(short)(p1.w>>16);
}

template<int CNT>
DEVINL floatx4 mfma_from_pk(const uintx4* pk, int grpBase,
                            const short8* __restrict__ wH,
                            const short8* __restrict__ wL, int lane)
{
    floatx4 a0 = {0.f, 0.f, 0.f, 0.f};
    floatx4 a1 = {0.f, 0.f, 0.f, 0.f};
    #pragma unroll
    for (int i = 0; i < CNT; ++i) {
        short8 ah, al;
        unpack_u44(pk[2 * i], pk[2 * i + 1], ah, al);
        short8 bh = wH[(grpBase + i) * 64 + lane];
        short8 bl = wL[(grpBase + i) * 64 + lane];
        a0 = __builtin_amdgcn_mfma_f32_16x16x32_bf16(ah, bh, a0, 0, 0, 0);
        a1 = __builtin_amdgcn_mfma_f32_16x16x32_bf16(ah, bl, a1, 0, 0, 0);
        a1 = __builtin_amdgcn_mfma_f32_16x16x32_bf16(al, bh, a1, 0, 0, 0);
    }
    return a0 + a1;
}

// =====================================================================
// Persistent bidirectional LSTM scan (split-precision bf16 hi/lo).
// R8: h loads forced-batched via inline-asm (26/24 dwordx4 + one vmcnt).
// Sync (proven R7): padded per-fuse-wave flags, per-wave vmcnt drain,
// ONE barrier/step (exch double-buffered), wave0 polls + LDS relay.
// =====================================================================
__global__ __launch_bounds__(256, 1) void scan_kernel(
    const unsigned short* __restrict__ wpackH,
    const unsigned short* __restrict__ wpackL,
    const float* __restrict__ pre,              // [d][t][b][3200] fp32
    uint32_t* hFP, uint32_t* hBP,               // packed h archives [257][16][800]
    unsigned int* flags)                        // this launch: [2 dirs][200*32 u32]
{
    __shared__ __align__(16) unsigned short wldsH[25600];   // 51.2 KB
    __shared__ __align__(16) unsigned short wldsL[25600];   // 51.2 KB
    __shared__ __align__(16) float exch[2][2][2][64][4];    // [par][nt][kh][lane][reg]
    __shared__ float cbuf[128];
    __shared__ unsigned int step_ready;
    int tid = threadIdx.x;
    int bid = blockIdx.x;
    int d = bid / 100, jc = bid % 100;
    unsigned int* dirFlags = flags + (size_t)d * 200 * FLAG_STRIDE;

    {   // load weight fragments once
        const short8* sh = (const short8*)wpackH + ((size_t)d * 100 + jc) * 3200;
        const short8* sl = (const short8*)wpackL + ((size_t)d * 100 + jc) * 3200;
        short8* dh = (short8*)wldsH;
        short8* dl = (short8*)wldsL;
        for (int i = tid; i < 3200; i += 256) { dh[i] = sh[i]; dl[i] = sl[i]; }
    }
    if (tid < 128) cbuf[tid] = 0.0f;
    if (tid == 0) step_ready = 0u;
    __syncthreads();

    int lane = tid & 63, w = tid >> 6;
    int nt = w & 1, kh = w >> 1;
    int bA = lane & 15, q = lane >> 4;
    int fb = (tid >> 3) & 15, fj = tid & 7;     // fuse indices (tid<128)

    uint32_t* hOutP = d ? hBP : hFP;
    const uint32_t* hInP = d ? hBP : hFP;
    const short8* wH8 = (const short8*)wldsH;
    const short8* wL8 = (const short8*)wldsL;

    for (int s = 0; s < L_SEQ; ++s) {
        int t = d ? (L_SEQ - 1 - s) : s;
        int islot = d ? (t + 1) : t;
        const uint32_t* base = hInP + (size_t)islot * HSLOT + bA * HID
                             + (kh ? 13 * 32 : 0) + q * 8;

        // prefetch pre gate values (independent of h) before waiting
        float pv[4];
        if (tid < 128) {
            const float* pp = pre + ((size_t)(d * L_SEQ + t) * BATCH + fb) * NGATE
                            + jc * 8 + fj;
            #pragma unroll
            for (int gate = 0; gate < 4; ++gate) pv[gate] = pp[gate * 800];
        }

        if (s > 0) {
            unsigned int need = (unsigned int)s;
            if (w == 0) {   // wave 0: poll all 200 padded flags in parallel
                bool ok;
                do {
                    unsigned v0 = __hip_atomic_load(&dirFlags[lane * FLAG_STRIDE],
                                    __ATOMIC_RELAXED, __HIP_MEMORY_SCOPE_AGENT);
                    unsigned v1 = __hip_atomic_load(&dirFlags[(lane + 64) * FLAG_STRIDE],
                                    __ATOMIC_RELAXED, __HIP_MEMORY_SCOPE_AGENT);
                    unsigned v2 = __hip_atomic_load(&dirFlags[(lane + 128) * FLAG_STRIDE],
                                    __ATOMIC_RELAXED, __HIP_MEMORY_SCOPE_AGENT);
                    unsigned v3 = (lane < 8)
                        ? __hip_atomic_load(&dirFlags[(lane + 192) * FLAG_STRIDE],
                                    __ATOMIC_RELAXED, __HIP_MEMORY_SCOPE_AGENT)
                        : 0xFFFFFFFFu;
                    ok = __all(v0 >= need && v1 >= need && v2 >= need && v3 >= need);
                } while (!ok);
                if (lane == 0)
                    __hip_atomic_store(&step_ready, need, __ATOMIC_RELAXED,
                                       __HIP_MEMORY_SCOPE_WORKGROUP);
            } else {        // waves 1-3: local LDS spin (no global traffic)
                while (__hip_atomic_load(&step_ready, __ATOMIC_RELAXED,
                                         __HIP_MEMORY_SCOPE_WORKGROUP) < need) {}
            }
        }

        // ---- forced-batch h loads + split MFMA ----
        uintx4 pk[26];
        floatx4 acc;
        if (kh == 0) {
            batch_load_26(base, pk);
            acc = mfma_from_pk<13>(pk, nt * 25, wH8, wL8, lane);
        } else {
            batch_load_24(base, pk);
            acc = mfma_from_pk<12>(pk, nt * 25 + 13, wH8, wL8, lane);
        }

        int p = s & 1;
        *(floatx4*)&exch[p][nt][kh][lane][0] = acc;
        __syncthreads();     // the ONE barrier per step

        if (tid < 128) {
            float G[4];
            #pragma unroll
            for (int gate = 0; gate < 4; ++gate) {
                int lr = gate * 8 + fj;
                int nt2 = lr >> 4, n = lr & 15;
                int ln = ((fb >> 2) << 4) | n;
                int rg = fb & 3;
                G[gate] = exch[p][nt2][0][ln][rg] + exch[p][nt2][1][ln][rg] + pv[gate];
            }
            float i_ = sigf(G[0]), f_ = sigf(G[1]);
            float g_ = tanhfast(G[2]), o_ = sigf(G[3]);
            float c = f_ * cbuf[tid] + i_ * g_;
            cbuf[tid] = c;
            float h = o_ * tanhfast(c);
            int oslot = d ? t : (t + 1);
            size_t oidx = (size_t)oslot * HSLOT + fb * HID + jc * 8 + fj;
            unsigned short hh = f2bf(h);
            uint32_t pko = (uint32_t)hh
                         | ((uint32_t)f2bf(h - bf2f(hh)) << 16);
            __hip_atomic_store(&hOutP[oidx], pko, __ATOMIC_RELAXED,
                               __HIP_MEMORY_SCOPE_AGENT);
            // drain only THIS wave's sc1 stores (no wbl2), then publish flag
            asm volatile("s_waitcnt vmcnt(0)" ::: "memory");
            if (lane == 0)
                __hip_atomic_store(&dirFlags[(jc * 2 + w) * FLAG_STRIDE],
                                   (unsigned int)(s + 1),
                                   __ATOMIC_RELAXED, __HIP_MEMORY_SCOPE_AGENT);
        }
        // no trailing barrier: exch double-buffered; next-step barrier orders reuse
    }
}

// =====================================================================
// pre1[d][t][b][r] = concat(h1f[t], h1b[t]) @ w_ih_l1[d].T + b_l1[d]  (fp32)
// split-precision 64x64-tile MFMA GEMM: M=4096 (t,b), N=3200, K=1600.
// =====================================================================
__global__ __launch_bounds__(256, 1) void gemm_pre1_kernel(
    const uint32_t* __restrict__ hFP, const uint32_t* __restrict__ hBP,
    const unsigned short* __restrict__ wih1H, const unsigned short* __restrict__ wih1L,
    const float* __restrict__ b1, float* __restrict__ pre1)
{
    int bid = blockIdx.x;
    int d = bid / 3200; int rst = bid % 3200;
    int mblk = rst / 50, nblk = rst % 50;
    __shared__ __align__(16) unsigned short AslH[64][40];
    __shared__ __align__(16) unsigned short AslL[64][40];
    __shared__ __align__(16) unsigned short BslH[64][40];
    __shared__ __align__(16) unsigned short BslL[64][40];
    int tid = threadIdx.x, lane = tid & 63, w = tid >> 6;
    int wm = w >> 1, wn = w & 1;
    floatx4 acc[2][2] = {};
    int row = tid >> 2, ch = tid & 3;
    int m_row = mblk * 64 + row;
    int t = m_row >> 4, bb = m_row & 15;
    int la = lane & 15, q8 = (lane >> 4) * 8;

    for (int kk = 0; kk < 50; ++kk) {
        int k0 = kk * 32 + ch * 8;
        size_t aoff = (kk < 25)
            ? ((size_t)(t + 1) * HSLOT + bb * HID + k0)
            : ((size_t)t * HSLOT + bb * HID + (k0 - 800));
        const uint32_t* ap = ((kk < 25) ? hFP : hBP) + aoff;
        uint4 p0 = *(const uint4*)ap;
        uint4 p1 = *(const uint4*)(ap + 4);
        short8 ah, al;
        ah[0]=(short)(p0.x&0xffffu); al[0]=(short)(p0.x>>16);
        ah[1]=(short)(p0.y&0xffffu); al[1]=(short)(p0.y>>16);
        ah[2]=(short)(p0.z&0xffffu); al[2]=(short)(p0.z>>16);
        ah[3]=(short)(p0.w&0xffffu); al[3]=(short)(p0.w>>16);
        ah[4]=(short)(p1.x&0xffffu); al[4]=(short)(p1.x>>16);
        ah[5]=(short)(p1.y&0xffffu); al[5]=(short)(p1.y>>16);
        ah[6]=(short)(p1.z&0xffffu); al[6]=(short)(p1.z>>16);
        ah[7]=(short)(p1.w&0xffffu); al[7]=(short)(p1.w>>16);
        *(short8*)&AslH[row][ch * 8] = ah;
        *(short8*)&AslL[row][ch * 8] = al;
        size_t boff = ((size_t)d * NGATE + nblk * 64 + row) * 1600 + kk * 32 + ch * 8;
        *(short8*)&BslH[row][ch * 8] = *(const short8*)(wih1H + boff);
        *(short8*)&BslL[row][ch * 8] = *(const short8*)(wih1L + boff);
        __syncthreads();
        #pragma unroll
        for (int ms = 0; ms < 2; ++ms) {
            short8 fah = *(const short8*)&AslH[wm * 32 + ms * 16 + la][q8];
            short8 fal = *(const short8*)&AslL[wm * 32 + ms * 16 + la][q8];
            #pragma unroll
            for (int ns = 0; ns < 2; ++ns) {
                short8 fbh = *(const short8*)&BslH[wn * 32 + ns * 16 + la][q8];
                short8 fbl = *(const short8*)&BslL[wn * 32 + ns * 16 + la][q8];
                acc[ms][ns] = __builtin_amdgcn_mfma_f32_16x16x32_bf16(fah, fbh, acc[ms][ns], 0, 0, 0);
                acc[ms][ns] = __builtin_amdgcn_mfma_f32_16x16x32_bf16(fah, fbl, acc[ms][ns], 0, 0, 0);
                acc[ms][ns] = __builtin_amdgcn_mfma_f32_16x16x32_bf16(fal, fbh, acc[ms][ns], 0, 0, 0);
            }
        }
        __syncthreads();
    }
    #pragma unroll
    for (int ms = 0; ms < 2; ++ms)
        #pragma unroll
        for (int ns = 0; ns < 2; ++ns)
            #pragma unroll
            for (int rg = 0; rg < 4; ++rg) {
                int m = mblk * 64 + wm * 32 + ms * 16 + (lane >> 4) * 4 + rg;
                int t2 = m >> 4, b2 = m & 15;
                int r = nblk * 64 + wn * 32 + ns * 16 + (lane & 15);
                float val = acc[ms][ns][rg] + b1[d * NGATE + r];
                pre1[((size_t)(d * L_SEQ + t2) * BATCH + b2) * NGATE + r] = val;
            }
}

// =====================================================================
// Head: logits -> softmax -> torsion angles.  One block per t.
// =====================================================================
__global__ __launch_bounds__(256) void head_kernel(
    const uint32_t* __restrict__ h2FP, const uint32_t* __restrict__ h2BP,
    const float* __restrict__ wlin, const float* __restrict__ blin,
    const float* __restrict__ alphabet, float* __restrict__ ang)
{
    int t = blockIdx.x, tid = threadIdx.x;
    __shared__ float lg[BATCH * NALPHA];
    __shared__ float probs[BATCH * NALPHA];
    for (int i = tid; i < BATCH * NALPHA; i += 256) {
        int a = i % NALPHA, b = i / NALPHA;
        size_t fo = (size_t)(t + 1) * HSLOT + b * HID;
        size_t bo = (size_t)t * HSLOT + b * HID;
        const float* wa = wlin + (size_t)a * 1600;
        float s = blin[a];
        #pragma unroll 4
        for (int k = 0; k < HID; ++k) {
            uint32_t uf = h2FP[fo + k], ub = h2BP[bo + k];
            float hf = bf2f((unsigned short)uf) + bf2f((unsigned short)(uf >> 16));
            float hb = bf2f((unsigned short)ub) + bf2f((unsigned short)(ub >> 16));
            s += hf * wa[k] + hb * wa[800 + k];
        }
        lg[b * NALPHA + a] = s;
    }
    __syncthreads();
    if (tid < BATCH) {
        int b = tid;
        float mx = -1e30f;
        for (int a = 0; a < NALPHA; ++a) mx = fmaxf(mx, lg[b * NALPHA + a]);
        float sum = 0.f;
        for (int a = 0; a < NALPHA; ++a) {
            float e = __expf(lg[b * NALPHA + a] - mx);
            probs[b * NALPHA + a] = e; sum += e;
        }
        float inv = 1.0f / sum;
        for (int a = 0; a < NALPHA; ++a) probs[b * NALPHA + a] *= inv;
    }
    __syncthreads();
    if (tid < BATCH * 3) {
        int b = tid / 3, i = tid % 3;
        float ss = 0.f, cc = 0.f;
        for (int a = 0; a < NALPHA; ++a) {
            float al = alphabet[a * 3 + i], p = probs[b * NALPHA + a];
            ss += p * sinf(al); cc += p * cosf(al);
        }
        ang[((size_t)t * BATCH + b) * 3 + i] = atan2f(ss, cc);
    }
}

// =====================================================================
// Sequential NeRF coordinate chain. One block; lane b handles batch b.
// =====================================================================
__global__ __launch_bounds__(64) void coords_kernel(
    const float* __restrict__ ang, float* __restrict__ out)
{
    int b = threadIdx.x;
    if (b >= BATCH) return;
    const float LENS[3] = {145.801f, 152.326f, 132.868f};
    const float ANGS[3] = {2.124f, 1.941f, 2.028f};
    float Ax = 0.f, Ay = 0.f, Az = 1.f;
    float Bx = 0.f, By = 1.f, Bz = 0.f;
    float Cx = 1.f, Cy = 0.f, Cz = 0.f;
    out[((size_t)0 * BATCH + b) * 3 + 0] = 0.f; out[((size_t)0 * BATCH + b) * 3 + 1] = 0.f; out[((size_t)0 * BATCH + b) * 3 + 2] = 1.f;
    out[((size_t)1 * BATCH + b) * 3 + 0] = 0.f; out[((size_t)1 * BATCH + b) * 3 + 1] = 1.f; out[((size_t)1 * BATCH + b) * 3 + 2] = 0.f;
    out[((size_t)2 * BATCH + b) * 3 + 0] = 1.f; out[((size_t)2 * BATCH + b) * 3 + 1] = 0.f; out[((size_t)2 * BATCH + b) * 3 + 2] = 0.f;
    for (int t = 0; t < L_SEQ; ++t) {
        #pragma unroll
        for (int i = 0; i < 3; ++i) {
            float P = ang[((size_t)t * BATCH + b) * 3 + i];
            float R = LENS[i], T = ANGS[i];
            float sT = sinf(T);
            float D2x = -R * cosf(T);
            float D2y = R * cosf(P) * sT;
            float D2z = R * sinf(P) * sT;
            float bx = Cx - Bx, by = Cy - By, bz = Cz - Bz;
            float binv = 1.0f / sqrtf(bx * bx + by * by + bz * bz);
            bx *= binv; by *= binv; bz *= binv;
            float ux = Bx - Ax, uy = By - Ay, uz = Bz - Az;
            float nx = uy * bz - uz * by;
            float ny = uz * bx - ux * bz;
            float nz = ux * by - uy * bx;
            float ninv = 1.0f / sqrtf(nx * nx + ny * ny + nz * nz);
            nx *= ninv; ny *= ninv; nz *= ninv;
            float cxx = ny * bz - nz * by;
            float cxy = nz * bx - nx * bz;
            float cxz = nx * by - ny * bx;
            float Dx = bx * D2x + cxx * D2y + nx * D2z + Cx;
            float Dy = by * D2x + cxy * D2y + ny * D2z + Cy;
            float Dz = bz * D2x + cxz * D2y + nz * D2z + Cz;
            size_t orow = 3 + (size_t)t * 3 + i;
            out[(orow * BATCH + b) * 3 + 0] = Dx;
            out[(orow * BATCH + b) * 3 + 1] = Dy;
            out[(orow * BATCH + b) * 3 + 2] = Dz;
            Ax = Bx; Ay = By; Az = Bz;
            Bx = Cx; By = Cy; Bz = Cz;
            Cx = Dx; Cy = Dy; Cz = Dz;
        }
    }
}

// =====================================================================
extern "C" void kernel_launch(void* const* d_in, const int* in_sizes, int n_in,
                              void* d_out, int out_size, void* d_ws, size_t ws_size,
                              hipStream_t stream)
{
    const float* x       = (const float*)d_in[0];
    const float* w_ih_l0 = (const float*)d_in[1];
    const float* w_hh_l0 = (const float*)d_in[2];
    const float* b_l0    = (const float*)d_in[3];
    const float* w_ih_l1 = (const float*)d_in[4];
    const float* w_hh_l1 = (const float*)d_in[5];
    const float* b_l1    = (const float*)d_in[6];
    const float* w_lin   = (const float*)d_in[7];
    const float* b_lin   = (const float*)d_in[8];
    const float* alphabet= (const float*)d_in[9];
    (void)in_sizes; (void)n_in; (void)out_size; (void)ws_size;

    char* ws = (char*)d_ws;
    unsigned int*   flags   = (unsigned int*)(ws + OFF_FLAGS);
    unsigned short* whhHi   = (unsigned short*)(ws + OFF_WHH_HI);
    unsigned short* whhLo   = (unsigned short*)(ws + OFF_WHH_LO);
    unsigned short* wih1Hi  = (unsigned short*)(ws + OFF_WIH1_HI);
    unsigned short* wih1Lo  = (unsigned short*)(ws + OFF_WIH1_LO);
    float*          pre     = (float*)(ws + OFF_PRE);       // pre0 then pre1 (aliased)
    uint32_t*       hFP     = (uint32_t*)(ws + OFF_H + 0 * SZ_HP);
    uint32_t*       hBP     = (uint32_t*)(ws + OFF_H + 1 * SZ_HP);
    uint32_t*       h2FP    = (uint32_t*)(ws + OFF_H + 2 * SZ_HP);
    uint32_t*       h2BP    = (uint32_t*)(ws + OFF_H + 3 * SZ_HP);
    float*          angbuf  = (float*)(ws + OFF_ANG);

    // zero flags (poison 0xAA would false-pass polls) + boundary h slots
    hipMemsetAsync(ws + OFF_FLAGS, 0, SZ_FLAGS, stream);
    const size_t slotB = (size_t)HSLOT * 4;
    hipMemsetAsync((char*)hFP, 0, slotB, stream);
    hipMemsetAsync((char*)hBP + 256 * slotB, 0, slotB, stream);
    hipMemsetAsync((char*)h2FP, 0, slotB, stream);
    hipMemsetAsync((char*)h2BP + 256 * slotB, 0, slotB, stream);

    pack_whh_kernel<<<5000, 256, 0, stream>>>(w_hh_l0, w_hh_l1, whhHi, whhLo);
    conv_wih1_kernel<<<5000, 256, 0, stream>>>(w_ih_l1, wih1Hi, wih1Lo);
    pre0_kernel<<<1600, 256, 0, stream>>>(x, w_ih_l0, b_l0, pre);

    // layer 0 bidirectional scan (flag region 0)
    scan_kernel<<<NBLK_SCAN, 256, 0, stream>>>(whhHi, whhLo, pre, hFP, hBP, flags);
    // layer 1 input projection (overwrites pre in place: pre0 dead, pre1 live)
    gemm_pre1_kernel<<<6400, 256, 0, stream>>>(hFP, hBP, wih1Hi, wih1Lo, b_l1, pre);
    // layer 1 bidirectional scan (flag region 1)
    constexpr size_t LOFF = SZ_WHH_L / 2;  // ushort elements per layer
    scan_kernel<<<NBLK_SCAN, 256, 0, stream>>>(whhHi + LOFF, whhLo + LOFF, pre,
                                               h2FP, h2BP, flags + 2 * 200 * FLAG_STRIDE);

    head_kernel<<<L_SEQ, 256, 0, stream>>>(h2FP, h2BP, w_lin, b_lin, alphabet, angbuf);
    coords_kernel<<<1, 64, 0, stream>>>(angbuf, (float*)d_out);
}